// Round 1
// baseline (904.896 us; speedup 1.0000x reference)
//
#include <hip/hip_runtime.h>

// ---------------------------------------------------------------------------
// PaiNN interaction layer, fp32.
//   ctx = silu(q@W1+b1)@W2+b2           [N,384]
//   x   = W_ij * ctx[idx_j]             [E,384]  (dq | dmu_r | dmu_mu)
//   dq  = segment_sum(x[:, :128], idx_i)
//   dmu = segment_sum(x_r*dir + x_m*mu[idx_j], idx_i)
//   out = (q+dq, mu+dmu)
// Strategy: CSR sort by idx_i, then wave-per-node register accumulation.
// ---------------------------------------------------------------------------

static __host__ __device__ inline size_t ws_align(size_t x) { return (x + 255) & ~(size_t)255; }

// ---------------- GEMM: C[M,Ncols] = act(A[M,128] @ B[128,Ncols] + bias) ----
// 64x64 tile, 256 threads, 4x4 microtile per thread. K=128 fully staged.
template <bool SILU>
__global__ __launch_bounds__(256, 2) void gemm_bias_act_kernel(
    const float* __restrict__ A, const float* __restrict__ B,
    const float* __restrict__ bias, float* __restrict__ C,
    int M, int Ncols)
{
    __shared__ float As[128][68];   // transposed A tile: As[k][row]
    __shared__ float Bs[128][68];   // Bs[k][col]

    const int t    = threadIdx.x;
    const int row0 = blockIdx.x * 64;
    const int col0 = blockIdx.y * 64;

    // Load A tile (64 rows x 128 k), store transposed.
    #pragma unroll
    for (int it = 0; it < 8; ++it) {
        int l    = t + 256 * it;       // 0..2047
        int r    = l >> 5;             // 0..63
        int k4   = (l & 31) << 2;      // 0,4,..,124
        int grow = row0 + r;
        float4 v = make_float4(0.f, 0.f, 0.f, 0.f);
        if (grow < M) v = *reinterpret_cast<const float4*>(A + (size_t)grow * 128 + k4);
        As[k4 + 0][r] = v.x; As[k4 + 1][r] = v.y;
        As[k4 + 2][r] = v.z; As[k4 + 3][r] = v.w;
    }
    // Load B tile (128 k x 64 cols). Ncols is a multiple of 64 -> no col guard.
    #pragma unroll
    for (int it = 0; it < 8; ++it) {
        int l  = t + 256 * it;         // 0..2047
        int k  = l >> 4;               // 0..127
        int c4 = (l & 15) << 2;        // 0,4,..,60
        float4 v = *reinterpret_cast<const float4*>(B + (size_t)k * Ncols + col0 + c4);
        *reinterpret_cast<float4*>(&Bs[k][c4]) = v;
    }
    __syncthreads();

    const int tx = t & 15, ty = t >> 4;
    float acc[4][4];
    #pragma unroll
    for (int i = 0; i < 4; ++i)
        #pragma unroll
        for (int j = 0; j < 4; ++j) acc[i][j] = 0.f;

    #pragma unroll 4
    for (int k = 0; k < 128; ++k) {
        float4 a = *reinterpret_cast<const float4*>(&As[k][ty * 4]);
        float4 b = *reinterpret_cast<const float4*>(&Bs[k][tx * 4]);
        acc[0][0] += a.x * b.x; acc[0][1] += a.x * b.y; acc[0][2] += a.x * b.z; acc[0][3] += a.x * b.w;
        acc[1][0] += a.y * b.x; acc[1][1] += a.y * b.y; acc[1][2] += a.y * b.z; acc[1][3] += a.y * b.w;
        acc[2][0] += a.z * b.x; acc[2][1] += a.z * b.y; acc[2][2] += a.z * b.z; acc[2][3] += a.z * b.w;
        acc[3][0] += a.w * b.x; acc[3][1] += a.w * b.y; acc[3][2] += a.w * b.z; acc[3][3] += a.w * b.w;
    }

    float4 bv = *reinterpret_cast<const float4*>(bias + col0 + tx * 4);
    #pragma unroll
    for (int i = 0; i < 4; ++i) {
        int grow = row0 + ty * 4 + i;
        if (grow >= M) continue;
        float4 o;
        o.x = acc[i][0] + bv.x; o.y = acc[i][1] + bv.y;
        o.z = acc[i][2] + bv.z; o.w = acc[i][3] + bv.w;
        if (SILU) {
            o.x = o.x / (1.f + __expf(-o.x));
            o.y = o.y / (1.f + __expf(-o.y));
            o.z = o.z / (1.f + __expf(-o.z));
            o.w = o.w / (1.f + __expf(-o.w));
        }
        *reinterpret_cast<float4*>(C + (size_t)grow * Ncols + col0 + tx * 4) = o;
    }
}

// ---------------- CSR build ------------------------------------------------
__global__ void zero_int_kernel(int* __restrict__ p, int n) {
    int i = blockIdx.x * 256 + threadIdx.x;
    if (i < n) p[i] = 0;
}

__global__ void count_kernel(const int* __restrict__ idx_i, int* __restrict__ cnt, int E) {
    int e = blockIdx.x * 256 + threadIdx.x;
    if (e < E) atomicAdd(&cnt[idx_i[e]], 1);
}

// single-block exclusive scan over N counts -> row_ptr[0..N]
__global__ __launch_bounds__(256) void scan_kernel(const int* __restrict__ cnt,
                                                   int* __restrict__ row_ptr, int N) {
    __shared__ int sums[256];
    __shared__ int offs[256];
    int t = threadIdx.x;
    int chunk = (N + 255) / 256;
    int lo = t * chunk;
    int hi = lo + chunk; if (hi > N) hi = N; if (lo > N) lo = N;
    int s = 0;
    for (int i = lo; i < hi; ++i) s += cnt[i];
    sums[t] = s;
    __syncthreads();
    if (t == 0) {
        int acc = 0;
        for (int k = 0; k < 256; ++k) { int v = sums[k]; offs[k] = acc; acc += v; }
    }
    __syncthreads();
    int acc = offs[t];
    for (int i = lo; i < hi; ++i) { row_ptr[i] = acc; acc += cnt[i]; }
    if (t == 255) row_ptr[N] = acc;   // == E (last chunks may be empty; acc==total)
}

__global__ void copy_int_kernel(const int* __restrict__ src, int* __restrict__ dst, int n) {
    int i = blockIdx.x * 256 + threadIdx.x;
    if (i < n) dst[i] = src[i];
}

__global__ void fill_kernel(const int* __restrict__ idx_i, int* __restrict__ cursor,
                            int* __restrict__ order, int E) {
    int e = blockIdx.x * 256 + threadIdx.x;
    if (e < E) {
        int pos = atomicAdd(&cursor[idx_i[e]], 1);
        order[pos] = e;
    }
}

// ---------------- node accumulation: one wave per node ---------------------
// lane owns features {2*lane, 2*lane+1}; accumulate dq (float2) and dmu (3x float2)
// in registers over the node's incoming edges; single coalesced write of out.
__global__ __launch_bounds__(256) void node_kernel(
    const float* __restrict__ q, const float* __restrict__ mu,
    const float* __restrict__ ctx, const float* __restrict__ W_ij,
    const float* __restrict__ dir_ij, const int* __restrict__ idx_j,
    const int* __restrict__ row_ptr, const int* __restrict__ order,
    float* __restrict__ out, int N)
{
    int wid  = (blockIdx.x * blockDim.x + threadIdx.x) >> 6;
    int lane = threadIdx.x & 63;
    if (wid >= N) return;

    int start = row_ptr[wid];
    int end   = row_ptr[wid + 1];
    const int f = lane * 2;

    float2 qa  = {0.f, 0.f};
    float2 ma0 = {0.f, 0.f}, ma1 = {0.f, 0.f}, ma2 = {0.f, 0.f};

    for (int p = start; p < end; ++p) {
        int e = order[p];           // wave-uniform
        int j = idx_j[e];           // wave-uniform
        const float* w  = W_ij + (size_t)e * 384;
        const float* cj = ctx  + (size_t)j * 384;
        const float* mj = mu   + (size_t)j * 384;
        float d0 = dir_ij[3 * (size_t)e + 0];
        float d1 = dir_ij[3 * (size_t)e + 1];
        float d2 = dir_ij[3 * (size_t)e + 2];

        float2 wq = *reinterpret_cast<const float2*>(w + f);
        float2 wr = *reinterpret_cast<const float2*>(w + 128 + f);
        float2 wm = *reinterpret_cast<const float2*>(w + 256 + f);
        float2 cq = *reinterpret_cast<const float2*>(cj + f);
        float2 cr = *reinterpret_cast<const float2*>(cj + 128 + f);
        float2 cm = *reinterpret_cast<const float2*>(cj + 256 + f);
        float2 m0 = *reinterpret_cast<const float2*>(mj + f);
        float2 m1 = *reinterpret_cast<const float2*>(mj + 128 + f);
        float2 m2 = *reinterpret_cast<const float2*>(mj + 256 + f);

        qa.x += wq.x * cq.x;  qa.y += wq.y * cq.y;
        float xr0 = wr.x * cr.x, xr1 = wr.y * cr.y;
        float xm0 = wm.x * cm.x, xm1 = wm.y * cm.y;
        ma0.x += xr0 * d0 + xm0 * m0.x;  ma0.y += xr1 * d0 + xm1 * m0.y;
        ma1.x += xr0 * d1 + xm0 * m1.x;  ma1.y += xr1 * d1 + xm1 * m1.y;
        ma2.x += xr0 * d2 + xm0 * m2.x;  ma2.y += xr1 * d2 + xm1 * m2.y;
    }

    // out_q = q + dq
    float2 qv = *reinterpret_cast<const float2*>(q + (size_t)wid * 128 + f);
    float2 oq; oq.x = qv.x + qa.x; oq.y = qv.y + qa.y;
    *reinterpret_cast<float2*>(out + (size_t)wid * 128 + f) = oq;

    // out_mu = mu + dmu
    const float* mbase = mu + (size_t)wid * 384;
    float* obase = out + (size_t)N * 128 + (size_t)wid * 384;
    float2 mv0 = *reinterpret_cast<const float2*>(mbase + f);
    float2 mv1 = *reinterpret_cast<const float2*>(mbase + 128 + f);
    float2 mv2 = *reinterpret_cast<const float2*>(mbase + 256 + f);
    float2 o0; o0.x = mv0.x + ma0.x; o0.y = mv0.y + ma0.y;
    float2 o1; o1.x = mv1.x + ma1.x; o1.y = mv1.y + ma1.y;
    float2 o2; o2.x = mv2.x + ma2.x; o2.y = mv2.y + ma2.y;
    *reinterpret_cast<float2*>(obase + f)       = o0;
    *reinterpret_cast<float2*>(obase + 128 + f) = o1;
    *reinterpret_cast<float2*>(obase + 256 + f) = o2;
}

// ---------------------------------------------------------------------------
extern "C" void kernel_launch(void* const* d_in, const int* in_sizes, int n_in,
                              void* d_out, int out_size, void* d_ws, size_t ws_size,
                              hipStream_t stream) {
    const float* q      = (const float*)d_in[0];
    const float* mu     = (const float*)d_in[1];
    const float* W_ij   = (const float*)d_in[2];
    const float* dir_ij = (const float*)d_in[3];
    const float* W1     = (const float*)d_in[4];
    const float* b1     = (const float*)d_in[5];
    const float* W2     = (const float*)d_in[6];
    const float* b2     = (const float*)d_in[7];
    const int*   idx_i  = (const int*)d_in[8];
    const int*   idx_j  = (const int*)d_in[9];

    const int N = in_sizes[0] / 128;     // 20000
    const int E = in_sizes[8];           // 320000
    float* out = (float*)d_out;

    // workspace carve-up
    char* ws = (char*)d_ws;
    size_t off = 0;
    float* ctx     = (float*)(ws + off); off += ws_align((size_t)N * 384 * 4);
    float* h       = (float*)(ws + off); off += ws_align((size_t)N * 128 * 4);
    int*   row_ptr = (int*)  (ws + off); off += ws_align((size_t)(N + 1) * 4);
    int*   cursor  = (int*)  (ws + off); off += ws_align((size_t)N * 4);
    int*   order   = (int*)  (ws + off); off += ws_align((size_t)E * 4);
    (void)ws_size; (void)n_in; (void)out_size;

    const int nblk_rows = (N + 63) / 64;
    const int eblk = (E + 255) / 256;
    const int nblk = (N + 255) / 256;

    // context net
    gemm_bias_act_kernel<true ><<<dim3(nblk_rows, 2), 256, 0, stream>>>(q, W1, b1, h,   N, 128);
    gemm_bias_act_kernel<false><<<dim3(nblk_rows, 6), 256, 0, stream>>>(h, W2, b2, ctx, N, 384);

    // CSR build (sort edges by destination idx_i)
    zero_int_kernel<<<nblk, 256, 0, stream>>>(cursor, N);
    count_kernel<<<eblk, 256, 0, stream>>>(idx_i, cursor, E);
    scan_kernel<<<1, 256, 0, stream>>>(cursor, row_ptr, N);
    copy_int_kernel<<<nblk, 256, 0, stream>>>(row_ptr, cursor, N);
    fill_kernel<<<eblk, 256, 0, stream>>>(idx_i, cursor, order, E);

    // per-node register accumulation + fused output add (no fp32 atomics)
    node_kernel<<<(N + 3) / 4, 256, 0, stream>>>(q, mu, ctx, W_ij, dir_ij, idx_j,
                                                 row_ptr, order, out, N);
}